// Round 16
// baseline (118.106 us; speedup 1.0000x reference)
//
#include <hip/hip_runtime.h>

struct CgPtrs { const float* p[9]; };               // p[l1*3+l2]
struct Desc  { int s00, s01, s10, s11, Ereg, E; };

__host__ __device__ constexpr int DSL(int s){ return s<2?1:(s==2?3:5); }   // 2l+1 of slot
__host__ __device__ constexpr int PRE(int s){ return s==0?0:(s==1?1:(s==2?2:5)); }
__host__ __device__ constexpr int LSL(int s){ return s<2?0:(s==2?1:2); }
__host__ __device__ constexpr int OFT(int a,int b){ return PRE(a)*10 + DSL(a)*PRE(b); }

// ---- kernel 1: per-edge (rank,class) into ws; g2b floats into out tail ----
__global__ __launch_bounds__(256) void prep_kernel(
    const int* __restrict__ sel00, const int* __restrict__ sel01,
    const int* __restrict__ sel10, const int* __restrict__ sel11,
    Desc d, int* __restrict__ rank, float* __restrict__ og)
{
    int u = blockIdx.x*256 + threadIdx.x;
    if (u < d.s00){ int e=sel00[u]; rank[e]=(u<<2)|0; og[e]=(float)u; return; } u-=d.s00;
    if (u < d.s01){ int e=sel01[u]; rank[e]=(u<<2)|1; og[e]=(float)u; return; } u-=d.s01;
    if (u < d.s10){ int e=sel10[u]; rank[e]=(u<<2)|2; og[e]=(float)u; return; } u-=d.s10;
    if (u < d.s11){ int e=sel11[u]; rank[e]=(u<<2)|3; og[e]=(float)u; return; }
}

// rows i=I0..I0+NR-1 of band S1, one S2 column-chunk, into acc[NR][10]
template<int S1,int S2,int I0,int NR>
__device__ __forceinline__ void rows_chunk(const float* __restrict__ x,
    const float* __restrict__ y, const CgPtrs& cg, float* acc)
{
    constexpr int d1=DSL(S1), d2=DSL(S2), K=d1*d2;
    constexpr int xo=OFT(S1,S2), yo=OFT(S2,S1), c0=PRE(S2);
    const float* __restrict__ wA = cg.p[LSL(S1)*3+LSL(S2)];   // cg_{l1,l2}[i][j][k]
    const float* __restrict__ wB = cg.p[LSL(S2)*3+LSL(S1)];   // cg_{l2,l1}[j][i][k]
    float xc[K], yc[K];
    #pragma unroll
    for (int k=0;k<K;++k) xc[k]=x[xo+k];
    #pragma unroll
    for (int k=0;k<K;++k) yc[k]=y[yo+k];
    #pragma unroll
    for (int r=0;r<NR;++r){
        #pragma unroll
        for (int j=0;j<d2;++j){
            float a = acc[r*10 + c0 + j];
            #pragma unroll
            for (int k=0;k<K;++k) a = fmaf(xc[k], wA[((I0+r)*d2+j)*K+k], a);
            #pragma unroll
            for (int k=0;k<K;++k) a = fmaf(yc[k], wB[(j*d1+I0+r)*K+k], a);
            acc[r*10 + c0 + j] = a;
        }
    }
}

template<int S1,int I0,int NR>
__device__ __forceinline__ void band_all(const float* x, const float* y,
                                         const CgPtrs& cg, float* acc)
{
    rows_chunk<S1,0,I0,NR>(x,y,cg,acc);
    rows_chunk<S1,1,I0,NR>(x,y,cg,acc);
    rows_chunk<S1,2,I0,NR>(x,y,cg,acc);
    rows_chunk<S1,3,I0,NR>(x,y,cg,acc);
}

// packed-col float4 store for c0/c2 (cols {0,2,3,4} of a 10-wide acc row)
__device__ __forceinline__ void stcols(float* p, const float* ar){
    *(float4*)p = make_float4(ar[0], ar[2], ar[3], ar[4]);
}
__device__ __forceinline__ void strow10(float* p, const float* ar){
    #pragma unroll
    for (int j=0;j<5;++j) *(float2*)(p+2*j) = make_float2(ar[2*j], ar[2*j+1]);
}

// ---- kernel 2: block = 128 edges staged in LDS; 8 waves = 2 halves x 4 row-groups ----
__global__ __launch_bounds__(512,6) void ham_kernel(
    const float* __restrict__ fn, const float* __restrict__ fe,
    const int* __restrict__ rank,
    CgPtrs cg, Desc d, float* __restrict__ out)
{
    __shared__ float xs[128*101];
    float* o00 = out;
    float* o01 = o00 + (size_t)d.s00*16;
    float* o10 = o01 + (size_t)d.s01*40;
    float* o11 = o10 + (size_t)d.s10*40;

    const int e0  = blockIdx.x*128;
    const int tid = threadIdx.x;
    const int nE  = min(128, d.E - e0);

    // stage 0.5*fe' rows, float4 global loads (self-tail: fn[e-Ereg] fused)
    for (int idx = tid; idx < nE*25; idx += 512){
        const int row = idx/25, q = idx - 25*row;
        const int e = e0 + row;
        float4 v = *(const float4*)(fe + (size_t)e*100 + 4*q);
        if (e >= d.Ereg){
            float4 w = *(const float4*)(fn + (size_t)(e - d.Ereg)*100 + 4*q);
            v.x += w.x; v.y += w.y; v.z += w.z; v.w += w.w;
        }
        float* dst = xs + row*101 + 4*q;
        dst[0]=0.5f*v.x; dst[1]=0.5f*v.y; dst[2]=0.5f*v.z; dst[3]=0.5f*v.w;
    }
    __syncthreads();

    const int lane = tid & 63;
    const int wid  = tid >> 6;                         // 0..7
    const int half = wid & 1;                          // edge half within the tile
    const int grp  = ((wid>>1) + blockIdx.x) & 3;      // rotate groups across blocks
    const int le   = half*64 + lane;                   // local edge 0..127
    const int e    = e0 + le;
    const bool act = (le < nE);
    float acc[40];
    #pragma unroll
    for (int i=0;i<40;++i) acc[i]=0.f;

    int rk=0, c=0;
    if (act){
        const int pk = rank[e];
        rk = pk >> 2; c = pk & 3;
        const float* x = xs + le*101;
        const float* y = (e >= d.Ereg) ? x : xs + (le^1)*101;   // inv(e)=e^1; self: y=x
        if      (grp==0){ band_all<0,0,1>(x,y,cg,acc);      // 10-rows 0,1,2,3
                          band_all<1,0,1>(x,y,cg,acc+10);
                          band_all<2,0,2>(x,y,cg,acc+20); }
        else if (grp==1){ band_all<2,2,1>(x,y,cg,acc);      // 10-rows 4,9
                          band_all<3,4,1>(x,y,cg,acc+10); }
        else if (grp==2){ band_all<3,0,2>(x,y,cg,acc); }    // 10-rows 5,6
        else            { band_all<3,2,2>(x,y,cg,acc); }    // 10-rows 7,8
    }

    if (act){
        if (grp==0){
            if (c==3){ float* o=o11+(size_t)rk*100;
                #pragma unroll
                for (int u=0;u<10;++u)
                    *(float4*)(o+4*u) = make_float4(acc[4*u],acc[4*u+1],acc[4*u+2],acc[4*u+3]); }
            else if (c==2){ float* o=o10+(size_t)rk*40;
                stcols(o+0,acc); stcols(o+4,acc+10); stcols(o+8,acc+20); stcols(o+12,acc+30); }
            else if (c==1){ float* o=o01+(size_t)rk*40;     // 10-rows {0,2,3} -> packed 0,1,2
                strow10(o+0,acc); strow10(o+10,acc+20); strow10(o+20,acc+30); }
            else { float* o=o00+(size_t)rk*16;
                stcols(o+0,acc); stcols(o+4,acc+20); stcols(o+8,acc+30); }
        } else if (grp==1){                                  // acc rows: 0 -> 10-row4, 1 -> 10-row9
            if (c==3){ float* o=o11+(size_t)rk*100;
                strow10(o+40,acc); strow10(o+90,acc+10); }
            else if (c==2){ float* o=o10+(size_t)rk*40;
                stcols(o+16,acc); stcols(o+36,acc+10); }
            else if (c==1){ float* o=o01+(size_t)rk*40;     // 10-row 4 -> packed row 3
                strow10(o+30,acc); }
            else { float* o=o00+(size_t)rk*16; stcols(o+12,acc); }
        } else if (grp==2){                                  // 10-rows 5,6 (type1 rows only)
            if (c==3){ float* o=o11+(size_t)rk*100;
                strow10(o+50,acc); strow10(o+60,acc+10); }
            else if (c==2){ float* o=o10+(size_t)rk*40;
                stcols(o+20,acc); stcols(o+24,acc+10); }
        } else {                                             // 10-rows 7,8
            if (c==3){ float* o=o11+(size_t)rk*100;
                strow10(o+70,acc); strow10(o+80,acc+10); }
            else if (c==2){ float* o=o10+(size_t)rk*40;
                stcols(o+28,acc); stcols(o+32,acc+10); }
        }
    }
}

extern "C" void kernel_launch(void* const* d_in, const int* in_sizes, int n_in,
                              void* d_out, int out_size, void* d_ws, size_t ws_size,
                              hipStream_t stream)
{
    const float* fn  = (const float*)d_in[0];
    const float* fe  = (const float*)d_in[1];
    CgPtrs cg;
    for (int i = 0; i < 9; ++i) cg.p[i] = (const float*)d_in[6 + i];
    const int* sel00 = (const int*)d_in[15];
    const int* sel01 = (const int*)d_in[16];
    const int* sel10 = (const int*)d_in[17];
    const int* sel11 = (const int*)d_in[18];

    const int N = in_sizes[0] / 100;
    const int E = in_sizes[3] / 2;

    Desc d;
    d.s00 = in_sizes[15]; d.s01 = in_sizes[16]; d.s10 = in_sizes[17]; d.s11 = in_sizes[18];
    d.Ereg = E - N;
    d.E = E;

    float* out = (float*)d_out;
    float* og  = out + (size_t)d.s00*16 + (size_t)d.s01*40 + (size_t)d.s10*40 + (size_t)d.s11*100;
    int* rank = (int*)d_ws;              // E ints

    prep_kernel<<<(E + 255)/256, 256, 0, stream>>>(sel00, sel01, sel10, sel11, d, rank, og);
    ham_kernel <<<(E + 127)/128, 512, 0, stream>>>(fn, fe, rank, cg, d, out);
}

// Round 17
// 113.247 us; speedup vs baseline: 1.0429x; 1.0429x over previous
//
#include <hip/hip_runtime.h>

struct CgPtrs { const float* p[9]; };               // p[l1*3+l2]
struct Desc  { int s00, s01, s10, s11, Ereg, E; };

__host__ __device__ constexpr int DSL(int s){ return s<2?1:(s==2?3:5); }   // 2l+1 of slot
__host__ __device__ constexpr int PRE(int s){ return s==0?0:(s==1?1:(s==2?2:5)); }
__host__ __device__ constexpr int LSL(int s){ return s<2?0:(s==2?1:2); }
__host__ __device__ constexpr int OFT(int a,int b){ return PRE(a)*10 + DSL(a)*PRE(b); }

// ---- kernel 1: per-edge (rank,class) into ws; g2b floats into out tail ----
__global__ __launch_bounds__(256) void prep_kernel(
    const int* __restrict__ sel00, const int* __restrict__ sel01,
    const int* __restrict__ sel10, const int* __restrict__ sel11,
    Desc d, int* __restrict__ rank, float* __restrict__ og)
{
    int u = blockIdx.x*256 + threadIdx.x;
    if (u < d.s00){ int e=sel00[u]; rank[e]=(u<<2)|0; og[e]=(float)u; return; } u-=d.s00;
    if (u < d.s01){ int e=sel01[u]; rank[e]=(u<<2)|1; og[e]=(float)u; return; } u-=d.s01;
    if (u < d.s10){ int e=sel10[u]; rank[e]=(u<<2)|2; og[e]=(float)u; return; } u-=d.s10;
    if (u < d.s11){ int e=sel11[u]; rank[e]=(u<<2)|3; og[e]=(float)u; return; }
}

// rows i=I0..I0+NR-1 of band S1, one S2 column-chunk, into acc[NR][10]
template<int S1,int S2,int I0,int NR>
__device__ __forceinline__ void rows_chunk(const float* __restrict__ x,
    const float* __restrict__ y, const CgPtrs& cg, float* acc)
{
    constexpr int d1=DSL(S1), d2=DSL(S2), K=d1*d2;
    constexpr int xo=OFT(S1,S2), yo=OFT(S2,S1), c0=PRE(S2);
    const float* __restrict__ wA = cg.p[LSL(S1)*3+LSL(S2)];   // cg_{l1,l2}[i][j][k]
    const float* __restrict__ wB = cg.p[LSL(S2)*3+LSL(S1)];   // cg_{l2,l1}[j][i][k]
    float xc[K], yc[K];
    #pragma unroll
    for (int k=0;k<K;++k) xc[k]=x[xo+k];
    #pragma unroll
    for (int k=0;k<K;++k) yc[k]=y[yo+k];
    #pragma unroll
    for (int r=0;r<NR;++r){
        #pragma unroll
        for (int j=0;j<d2;++j){
            float a = acc[r*10 + c0 + j];
            #pragma unroll
            for (int k=0;k<K;++k) a = fmaf(xc[k], wA[((I0+r)*d2+j)*K+k], a);
            #pragma unroll
            for (int k=0;k<K;++k) a = fmaf(yc[k], wB[(j*d1+I0+r)*K+k], a);
            acc[r*10 + c0 + j] = a;
        }
    }
}

template<int S1,int I0,int NR>
__device__ __forceinline__ void band_all(const float* x, const float* y,
                                         const CgPtrs& cg, float* acc)
{
    rows_chunk<S1,0,I0,NR>(x,y,cg,acc);
    rows_chunk<S1,1,I0,NR>(x,y,cg,acc);
    rows_chunk<S1,2,I0,NR>(x,y,cg,acc);
    rows_chunk<S1,3,I0,NR>(x,y,cg,acc);
}

// packed-col float4 store for c0/c2 (cols {0,2,3,4} of a 10-wide acc row)
__device__ __forceinline__ void stcols(float* p, const float* ar){
    *(float4*)p = make_float4(ar[0], ar[2], ar[3], ar[4]);
}
__device__ __forceinline__ void strow10(float* p, const float* ar){
    #pragma unroll
    for (int j=0;j<5;++j) *(float2*)(p+2*j) = make_float2(ar[2*j], ar[2*j+1]);
}

// ---- kernel 2: block = 64 edges staged in LDS; wave = balanced row-group ----
__global__ __launch_bounds__(256,6) void ham_kernel(
    const float* __restrict__ fn, const float* __restrict__ fe,
    const int* __restrict__ rank,
    CgPtrs cg, Desc d, float* __restrict__ out)
{
    __shared__ float xs[64*101];
    float* o00 = out;
    float* o01 = o00 + (size_t)d.s00*16;
    float* o10 = o01 + (size_t)d.s01*40;
    float* o11 = o10 + (size_t)d.s10*40;

    const int e0  = blockIdx.x*64;
    const int tid = threadIdx.x;
    const int nE  = min(64, d.E - e0);

    // stage 0.5*fe' rows, float4 global loads (self-tail: fn[e-Ereg] fused)
    for (int idx = tid; idx < nE*25; idx += 256){
        const int row = idx/25, q = idx - 25*row;
        const int e = e0 + row;
        float4 v = *(const float4*)(fe + (size_t)e*100 + 4*q);
        if (e >= d.Ereg){
            float4 w = *(const float4*)(fn + (size_t)(e - d.Ereg)*100 + 4*q);
            v.x += w.x; v.y += w.y; v.z += w.z; v.w += w.w;
        }
        float* dst = xs + row*101 + 4*q;
        dst[0]=0.5f*v.x; dst[1]=0.5f*v.y; dst[2]=0.5f*v.z; dst[3]=0.5f*v.w;
    }
    __syncthreads();

    const int lane = tid & 63;
    const int grp  = ((tid>>6) + blockIdx.x) & 3;      // rotate groups across blocks
    const int e = e0 + lane;
    const bool act = (lane < nE);
    float acc[40];
    #pragma unroll
    for (int i=0;i<40;++i) acc[i]=0.f;

    int rk=0, c=0;
    if (act){
        const int pk = rank[e];
        rk = pk >> 2; c = pk & 3;
        const float* x = xs + lane*101;
        const float* y = (e >= d.Ereg) ? x : xs + (lane^1)*101;  // inv(e)=e^1; self: y=x
        if      (grp==0){ band_all<0,0,1>(x,y,cg,acc);      // 10-rows 0,1,2,3
                          band_all<1,0,1>(x,y,cg,acc+10);
                          band_all<2,0,2>(x,y,cg,acc+20); }
        else if (grp==1){ band_all<2,2,1>(x,y,cg,acc);      // 10-rows 4,9
                          band_all<3,4,1>(x,y,cg,acc+10); }
        else if (grp==2){ band_all<3,0,2>(x,y,cg,acc); }    // 10-rows 5,6
        else            { band_all<3,2,2>(x,y,cg,acc); }    // 10-rows 7,8
    }

    if (act){
        if (grp==0){
            if (c==3){ float* o=o11+(size_t)rk*100;
                #pragma unroll
                for (int u=0;u<10;++u)
                    *(float4*)(o+4*u) = make_float4(acc[4*u],acc[4*u+1],acc[4*u+2],acc[4*u+3]); }
            else if (c==2){ float* o=o10+(size_t)rk*40;
                stcols(o+0,acc); stcols(o+4,acc+10); stcols(o+8,acc+20); stcols(o+12,acc+30); }
            else if (c==1){ float* o=o01+(size_t)rk*40;     // 10-rows {0,2,3} -> packed 0,1,2
                strow10(o+0,acc); strow10(o+10,acc+20); strow10(o+20,acc+30); }
            else { float* o=o00+(size_t)rk*16;
                stcols(o+0,acc); stcols(o+4,acc+20); stcols(o+8,acc+30); }
        } else if (grp==1){                                  // acc rows: 0 -> 10-row4, 1 -> 10-row9
            if (c==3){ float* o=o11+(size_t)rk*100;
                strow10(o+40,acc); strow10(o+90,acc+10); }
            else if (c==2){ float* o=o10+(size_t)rk*40;
                stcols(o+16,acc); stcols(o+36,acc+10); }
            else if (c==1){ float* o=o01+(size_t)rk*40;     // 10-row 4 -> packed row 3
                strow10(o+30,acc); }
            else { float* o=o00+(size_t)rk*16; stcols(o+12,acc); }
        } else if (grp==2){                                  // 10-rows 5,6 (type1 rows only)
            if (c==3){ float* o=o11+(size_t)rk*100;
                strow10(o+50,acc); strow10(o+60,acc+10); }
            else if (c==2){ float* o=o10+(size_t)rk*40;
                stcols(o+20,acc); stcols(o+24,acc+10); }
        } else {                                             // 10-rows 7,8
            if (c==3){ float* o=o11+(size_t)rk*100;
                strow10(o+70,acc); strow10(o+80,acc+10); }
            else if (c==2){ float* o=o10+(size_t)rk*40;
                stcols(o+28,acc); stcols(o+32,acc+10); }
        }
    }
}

extern "C" void kernel_launch(void* const* d_in, const int* in_sizes, int n_in,
                              void* d_out, int out_size, void* d_ws, size_t ws_size,
                              hipStream_t stream)
{
    const float* fn  = (const float*)d_in[0];
    const float* fe  = (const float*)d_in[1];
    CgPtrs cg;
    for (int i = 0; i < 9; ++i) cg.p[i] = (const float*)d_in[6 + i];
    const int* sel00 = (const int*)d_in[15];
    const int* sel01 = (const int*)d_in[16];
    const int* sel10 = (const int*)d_in[17];
    const int* sel11 = (const int*)d_in[18];

    const int N = in_sizes[0] / 100;
    const int E = in_sizes[3] / 2;

    Desc d;
    d.s00 = in_sizes[15]; d.s01 = in_sizes[16]; d.s10 = in_sizes[17]; d.s11 = in_sizes[18];
    d.Ereg = E - N;
    d.E = E;

    float* out = (float*)d_out;
    float* og  = out + (size_t)d.s00*16 + (size_t)d.s01*40 + (size_t)d.s10*40 + (size_t)d.s11*100;
    int* rank = (int*)d_ws;              // E ints

    prep_kernel<<<(E + 255)/256, 256, 0, stream>>>(sel00, sel01, sel10, sel11, d, rank, og);
    ham_kernel <<<(E + 63)/64,   256, 0, stream>>>(fn, fe, rank, cg, d, out);
}

// Round 18
// 94.108 us; speedup vs baseline: 1.2550x; 1.2034x over previous
//
#include <hip/hip_runtime.h>

struct CgPtrs { const float* p[9]; };               // p[l1*3+l2]
struct Desc  { int s00, s01, s10, s11, Ereg, E; };

__host__ __device__ constexpr int DSL(int s){ return s<2?1:(s==2?3:5); }   // 2l+1 of slot
__host__ __device__ constexpr int PRE(int s){ return s==0?0:(s==1?1:(s==2?2:5)); }
__host__ __device__ constexpr int LSL(int s){ return s<2?0:(s==2?1:2); }
__host__ __device__ constexpr int OFT(int a,int b){ return PRE(a)*10 + DSL(a)*PRE(b); }

// ---- kernel 1: per-edge (rank,class) into ws ----
__global__ __launch_bounds__(256) void prep_kernel(
    const int* __restrict__ sel00, const int* __restrict__ sel01,
    const int* __restrict__ sel10, const int* __restrict__ sel11,
    Desc d, int* __restrict__ rank)
{
    int u = blockIdx.x*256 + threadIdx.x;
    if (u < d.s00){ int e=sel00[u]; rank[e]=(u<<2)|0; return; } u-=d.s00;
    if (u < d.s01){ int e=sel01[u]; rank[e]=(u<<2)|1; return; } u-=d.s01;
    if (u < d.s10){ int e=sel10[u]; rank[e]=(u<<2)|2; return; } u-=d.s10;
    if (u < d.s11){ int e=sel11[u]; rank[e]=(u<<2)|3; return; }
}

// rows i=I0..I0+NR-1 of band S1, one S2 column-chunk, into acc[NR][10]
template<int S1,int S2,int I0,int NR>
__device__ __forceinline__ void rows_chunk(const float* __restrict__ x,
    const float* __restrict__ y, const CgPtrs& cg, float* acc)
{
    constexpr int d1=DSL(S1), d2=DSL(S2), K=d1*d2;
    constexpr int xo=OFT(S1,S2), yo=OFT(S2,S1), c0=PRE(S2);
    const float* __restrict__ wA = cg.p[LSL(S1)*3+LSL(S2)];   // cg_{l1,l2}[i][j][k]
    const float* __restrict__ wB = cg.p[LSL(S2)*3+LSL(S1)];   // cg_{l2,l1}[j][i][k]
    float xc[K], yc[K];
    #pragma unroll
    for (int k=0;k<K;++k) xc[k]=x[xo+k];
    #pragma unroll
    for (int k=0;k<K;++k) yc[k]=y[yo+k];
    #pragma unroll
    for (int r=0;r<NR;++r){
        #pragma unroll
        for (int j=0;j<d2;++j){
            float a = acc[r*10 + c0 + j];
            #pragma unroll
            for (int k=0;k<K;++k) a = fmaf(xc[k], wA[((I0+r)*d2+j)*K+k], a);
            #pragma unroll
            for (int k=0;k<K;++k) a = fmaf(yc[k], wB[(j*d1+I0+r)*K+k], a);
            acc[r*10 + c0 + j] = a;
        }
    }
}

template<int S1,int I0,int NR>
__device__ __forceinline__ void band_all(const float* x, const float* y,
                                         const CgPtrs& cg, float* acc)
{
    rows_chunk<S1,0,I0,NR>(x,y,cg,acc);
    rows_chunk<S1,1,I0,NR>(x,y,cg,acc);
    rows_chunk<S1,2,I0,NR>(x,y,cg,acc);
    rows_chunk<S1,3,I0,NR>(x,y,cg,acc);
}

// packed element map: output word -> full 10x10 word, per class
template<int C>
__device__ __forceinline__ int pmap(int off){
    if constexpr (C==3){ return off; }
    else if constexpr (C==1){            // 4x10: rows packed {0,2,3,4}, cols full
        int r = off/10, cl = off - 10*r;
        return (r==0?0:r+1)*10 + cl;
    } else if constexpr (C==2){          // 10x4: rows full, cols packed
        int r = off>>2, cl = off&3;
        return r*10 + (cl==0?0:cl+1);
    } else {                             // 4x4: both packed
        int r = off>>2, cl = off&3;
        return (r==0?0:r+1)*10 + (cl==0?0:cl+1);
    }
}

// coalesced per-class writeout from the LDS-assembled 10x10 mats
template<int C>
__device__ __forceinline__ void writeclass(
    int tid, const float* __restrict__ xs, const unsigned char* __restrict__ pos8,
    const int* __restrict__ basep, const int* __restrict__ cntp, float* __restrict__ o)
{
    constexpr int RC = (C==0)?16:((C==3)?100:40);
    constexpr int RC2 = RC/2;
    const int n = cntp[C];
    const int b = basep[C];
    for (int t = tid; t < n*RC2; t += 256){
        const int m   = t / RC2;
        const int off = 2*(t - m*RC2);
        const float* src = xs + (int)pos8[C*64 + m]*101;
        float v0 = src[pmap<C>(off)];
        float v1 = src[pmap<C>(off+1)];
        *(float2*)(o + (size_t)(b+m)*RC + off) = make_float2(v0, v1);
    }
}

// ---- kernel 2: block = 64 edges; wave = balanced row-group; LDS-reassembled coalesced writes ----
__global__ __launch_bounds__(256,6) void ham_kernel(
    const float* __restrict__ fn, const float* __restrict__ fe,
    const int* __restrict__ rank,
    CgPtrs cg, Desc d, float* __restrict__ out, float* __restrict__ og)
{
    __shared__ float xs[64*101];
    __shared__ unsigned char pos8[256];
    __shared__ int basep[4], cntp[4];

    float* o00 = out;
    float* o01 = o00 + (size_t)d.s00*16;
    float* o10 = o01 + (size_t)d.s01*40;
    float* o11 = o10 + (size_t)d.s10*40;

    const int e0  = blockIdx.x*64;
    const int tid = threadIdx.x;
    const int nE  = min(64, d.E - e0);

    // stage 0.5*fe' rows, float4 global loads (self-tail: fn[e-Ereg] fused)
    for (int idx = tid; idx < nE*25; idx += 256){
        const int row = idx/25, q = idx - 25*row;
        const int e = e0 + row;
        float4 v = *(const float4*)(fe + (size_t)e*100 + 4*q);
        if (e >= d.Ereg){
            float4 w = *(const float4*)(fn + (size_t)(e - d.Ereg)*100 + 4*q);
            v.x += w.x; v.y += w.y; v.z += w.z; v.w += w.w;
        }
        float* dst = xs + row*101 + 4*q;
        dst[0]=0.5f*v.x; dst[1]=0.5f*v.y; dst[2]=0.5f*v.z; dst[3]=0.5f*v.w;
    }
    // wave 0: class metadata (pos/base/cnt via ballot)
    if (tid < 4) cntp[tid] = 0;
    if (tid < 64){
        const bool valid = (tid < nE);
        const int pk = valid ? rank[e0 + tid] : 0;
        const int c_me = valid ? (pk & 3) : -1;
        const unsigned long long b0 = __ballot(c_me==0), b1 = __ballot(c_me==1),
                                 b2 = __ballot(c_me==2), b3 = __ballot(c_me==3);
        if (valid){
            const unsigned long long mym = (c_me==0)?b0:(c_me==1)?b1:(c_me==2)?b2:b3;
            const int p = __popcll(mym & ((1ull<<tid)-1ull));
            pos8[c_me*64 + p] = (unsigned char)tid;
            if (p == 0){ basep[c_me] = pk >> 2; cntp[c_me] = __popcll(mym); }
        }
    }
    __syncthreads();

    const int lane = tid & 63;
    const int grp  = ((tid>>6) + blockIdx.x) & 3;      // rotate groups across blocks
    const int e = e0 + lane;
    const bool act = (lane < nE);
    float acc[40];
    #pragma unroll
    for (int i=0;i<40;++i) acc[i]=0.f;

    if (act){
        if (grp == 0) og[e] = (float)(rank[e] >> 2);   // g2b, coalesced stream
        const float* x = xs + lane*101;
        const float* y = (e >= d.Ereg) ? x : xs + (lane^1)*101;  // inv(e)=e^1; self: y=x
        if      (grp==0){ band_all<0,0,1>(x,y,cg,acc);      // 10-rows 0,1,2,3
                          band_all<1,0,1>(x,y,cg,acc+10);
                          band_all<2,0,2>(x,y,cg,acc+20); }
        else if (grp==1){ band_all<2,2,1>(x,y,cg,acc);      // 10-rows 4,9
                          band_all<3,4,1>(x,y,cg,acc+10); }
        else if (grp==2){ band_all<3,0,2>(x,y,cg,acc); }    // 10-rows 5,6
        else            { band_all<3,2,2>(x,y,cg,acc); }    // 10-rows 7,8
    }
    __syncthreads();                      // all xs reads (incl. partner rows) done

    if (act){
        float* dst = xs + lane*101;
        if (grp==0){
            #pragma unroll
            for (int u=0;u<40;++u) dst[u] = acc[u];
        } else if (grp==1){
            #pragma unroll
            for (int u=0;u<10;++u) dst[40+u] = acc[u];
            #pragma unroll
            for (int u=0;u<10;++u) dst[90+u] = acc[10+u];
        } else if (grp==2){
            #pragma unroll
            for (int u=0;u<20;++u) dst[50+u] = acc[u];
        } else {
            #pragma unroll
            for (int u=0;u<20;++u) dst[70+u] = acc[u];
        }
    }
    __syncthreads();                      // full 10x10 mats assembled in xs

    writeclass<0>(tid, xs, pos8, basep, cntp, o00);
    writeclass<1>(tid, xs, pos8, basep, cntp, o01);
    writeclass<2>(tid, xs, pos8, basep, cntp, o10);
    writeclass<3>(tid, xs, pos8, basep, cntp, o11);
}

extern "C" void kernel_launch(void* const* d_in, const int* in_sizes, int n_in,
                              void* d_out, int out_size, void* d_ws, size_t ws_size,
                              hipStream_t stream)
{
    const float* fn  = (const float*)d_in[0];
    const float* fe  = (const float*)d_in[1];
    CgPtrs cg;
    for (int i = 0; i < 9; ++i) cg.p[i] = (const float*)d_in[6 + i];
    const int* sel00 = (const int*)d_in[15];
    const int* sel01 = (const int*)d_in[16];
    const int* sel10 = (const int*)d_in[17];
    const int* sel11 = (const int*)d_in[18];

    const int N = in_sizes[0] / 100;
    const int E = in_sizes[3] / 2;

    Desc d;
    d.s00 = in_sizes[15]; d.s01 = in_sizes[16]; d.s10 = in_sizes[17]; d.s11 = in_sizes[18];
    d.Ereg = E - N;
    d.E = E;

    float* out = (float*)d_out;
    float* og  = out + (size_t)d.s00*16 + (size_t)d.s01*40 + (size_t)d.s10*40 + (size_t)d.s11*100;
    int* rank = (int*)d_ws;              // E ints

    prep_kernel<<<(E + 255)/256, 256, 0, stream>>>(sel00, sel01, sel10, sel11, d, rank);
    ham_kernel <<<(E + 63)/64,   256, 0, stream>>>(fn, fe, rank, cg, d, out, og);
}